// Round 3
// baseline (215.659 us; speedup 1.0000x reference)
//
#include <hip/hip_runtime.h>
#include <hip/hip_bf16.h>
#include <cstdint>
#include <cstddef>

#define N_ATOMS 10000
#define NSTRUCT 100
#define NP 4
#define NS 4
#define NF2 2560      // 4 l x 640 block-aligned symmetric-packed features
#define HID 256
#define APAD 10240    // 80 tiles of 128

// prep-kernel block ranges
#define PB_FEAT  2500                     // [0,2500): power spectrum, 4 atoms/block
#define PB_W0    (PB_FEAT + 2560)         // w0cvt: 8(n) x 80(k) x 4(p)
#define PB_W1    (PB_W0 + 256)            // w1cvt: 8 x 8 x 4
#define PB_ZERO  (PB_W1 + 300)            // fh tail rows 10000..10239
#define PB_TOTAL (PB_ZERO + 1)            // + out zero

typedef __attribute__((ext_vector_type(8))) _Float16 f16x8;
typedef __attribute__((ext_vector_type(8))) ushort u16x8;
typedef __attribute__((ext_vector_type(4))) float f32x4;

__device__ __forceinline__ float silu(float x) {
  return x / (1.f + __expf(-x));
}
__device__ __forceinline__ ushort f2h(float x) {
  _Float16 h = (_Float16)x;
  return *reinterpret_cast<ushort*>(&h);
}
// chunk c in [0,80) -> (row q, r-block b). Row q owns blocks q>>3 .. 3.
__device__ __forceinline__ void cdec(int c, int& q, int& b) {
  if (c < 32)      { q = c >> 2; b = c & 3; }
  else if (c < 56) { int x = c - 32; int j = (x * 171) >> 9; q = 8 + j; b = 1 + (x - j * 3); }
  else if (c < 72) { int x = c - 56; q = 16 + (x >> 1); b = 2 + (x & 1); }
  else             { q = 24 + (c - 72); b = 3; }
}

typedef __attribute__((address_space(3))) uint32_t lds_u32;
typedef __attribute__((address_space(3))) ushort lds_ushort;
typedef const __attribute__((address_space(1))) uint32_t glb_u32;
__device__ __forceinline__ void glds16(const ushort* g, ushort* l) {
  __builtin_amdgcn_global_load_lds((glb_u32*)g, (lds_u32*)l, 16, 0, 0);
}
// inline-asm ds_read_b128: opaque to the compiler's LDS-DMA alias tracking,
// so no compiler-inserted vmcnt(0) between global_load_lds and these reads.
__device__ __forceinline__ f16x8 dsr(uint32_t addr) {
  f16x8 r;
  asm volatile("ds_read_b128 %0, %1" : "=v"(r) : "v"(addr));
  return r;
}

// ---------------- Kernel P: fused prep -------------------------------------
__global__ __launch_bounds__(256) void prep_kernel(
    const float* __restrict__ c0, const float* __restrict__ c1,
    const float* __restrict__ c2, const float* __restrict__ c3,
    const float* __restrict__ W0, const float* __restrict__ W1,
    ushort* __restrict__ fh, ushort* __restrict__ W0t,
    ushort* __restrict__ W1t, float* __restrict__ out) {
  __shared__ float shbuf[2048];   // feat: 4 waves x 512; cvt: 32x33
  int b = blockIdx.x;
  int tid = threadIdx.x;

  if (b < PB_FEAT) {
    // ---- power spectrum, one WAVE per atom, 5 chunks/lane ----
    int wv = tid >> 6, lane = tid & 63;
    int a = b * 4 + wv;
    float* cs = shbuf + wv * 512;
    for (int i = 0; i < 8; ++i) {
      int e = lane + i * 64;
      float v;
      if (e < 32)       v = c0[a * 32  + e];
      else if (e < 128) v = c1[a * 96  + (e - 32)];
      else if (e < 288) v = c2[a * 160 + (e - 128)];
      else              v = c3[a * 224 + (e - 288)];
      cs[e] = v;
    }
    __syncthreads();
    const float cg[4]  = {1.0f, 0.5773502691896258f, 0.4472135954999579f, 0.3779644730092272f};
    const int  off[4]  = {0, 32, 128, 288};
    const int  nm[4]   = {1, 3, 5, 7};
#pragma unroll
    for (int t = 0; t < 5; ++t) {
      int cc = lane + t * 64;           // [0,320), all lanes busy
      int l = cc / 80, c = cc - l * 80;
      int q, bb; cdec(c, q, bb);
      int rb = bb * 8;
      const float* base = cs + off[l];
      float s[8] = {0.f, 0.f, 0.f, 0.f, 0.f, 0.f, 0.f, 0.f};
      for (int m = 0; m < nm[l]; ++m) {
        float bq = base[m * 32 + q];
        float4 v0 = *reinterpret_cast<const float4*>(&base[m * 32 + rb]);
        float4 v1 = *reinterpret_cast<const float4*>(&base[m * 32 + rb + 4]);
        s[0] += bq * v0.x; s[1] += bq * v0.y; s[2] += bq * v0.z; s[3] += bq * v0.w;
        s[4] += bq * v1.x; s[5] += bq * v1.y; s[6] += bq * v1.z; s[7] += bq * v1.w;
      }
      u16x8 o;
#pragma unroll
      for (int u = 0; u < 8; ++u) o[u] = f2h(s[u] * cg[l]);
      *reinterpret_cast<u16x8*>(&fh[(size_t)a * NF2 + cc * 8]) = o;
    }
  } else if (b < PB_W0) {
    // ---- W0' fold -> W0t [p][h][fk] fp16 ----
    int idx = b - PB_FEAT;
    int nx = idx & 7;
    int rest = idx >> 3;
    int ky = rest % 80, p = rest / 80;
    int kt = ky * 32, nt = nx * 32;
    int lx = tid & 31, ly = tid >> 5;
    float (*t)[33] = (float(*)[33])shbuf;
    const float* src = W0 + (size_t)p * 4096 * HID;
#pragma unroll
    for (int i = 0; i < 4; ++i) {
      int kf = kt + ly + i * 8;
      int l = kf / 640, w = kf - l * 640;
      int c = w >> 3, s = w & 7;
      int q, bb; cdec(c, q, bb);
      int r = bb * 8 + s;
      float v = 0.f;
      if (r >= q) {
        v = src[(size_t)(l * 1024 + q * 32 + r) * HID + nt + lx];
        if (r > q) v += src[(size_t)(l * 1024 + r * 32 + q) * HID + nt + lx];
      }
      t[ly + i * 8][lx] = v;
    }
    __syncthreads();
    ushort* dst = W0t + (size_t)p * HID * NF2;
#pragma unroll
    for (int i = 0; i < 4; ++i)
      dst[(size_t)(nt + ly + i * 8) * NF2 + kt + lx] = f2h(t[lx][ly + i * 8]);
  } else if (b < PB_W1) {
    int idx = b - PB_W0;
    int nx = idx & 7, ky = (idx >> 3) & 7, p = idx >> 6;
    int kt = ky * 32, nt = nx * 32;
    int lx = tid & 31, ly = tid >> 5;
    float (*t)[33] = (float(*)[33])shbuf;
    const float* src = W1 + (size_t)p * HID * HID;
#pragma unroll
    for (int i = 0; i < 4; ++i)
      t[ly + i * 8][lx] = src[(size_t)(kt + ly + i * 8) * HID + nt + lx];
    __syncthreads();
    ushort* dst = W1t + (size_t)p * HID * HID;
#pragma unroll
    for (int i = 0; i < 4; ++i)
      dst[(size_t)(nt + ly + i * 8) * HID + kt + lx] = f2h(t[lx][ly + i * 8]);
  } else if (b < PB_ZERO) {
    int idx = b - PB_W1;
    size_t e = (size_t)idx * 2048 + tid * 8;
    u16x8 z = (u16x8){0, 0, 0, 0, 0, 0, 0, 0};
    *reinterpret_cast<u16x8*>(&fh[(size_t)N_ATOMS * NF2 + e]) = z;
  } else {
    if (tid < NSTRUCT) out[tid] = 0.f;
  }
}

// ---------------- Kernel B: fp16 MFMA GEMM0, 128x128, BK=32 ----------------
// 3-deep pipeline: 3 LDS buffers (48KB); tile t+2 staged at TOP of step t
// into the buffer whose reads finished at step t-1 (protected by that step's
// barrier). Steady-state wait vmcnt(4) targets a tile issued ~2 full steps
// earlier (~800 cyc flight >= L3/HBM latency). One barrier per step.
__global__ __launch_bounds__(256) void gemm0_mfma(
    const ushort* __restrict__ fh, const ushort* __restrict__ W0t,
    const float* __restrict__ combW, const int* __restrict__ species,
    ushort* __restrict__ h0f) {
  __shared__ ushort sh[24576];   // 48KB: 3 x {A 8KB | B 8KB}
  int tid = threadIdx.x;
  int linear = blockIdx.y * 8 + blockIdx.x;
  int xc = linear & 7, sq = linear >> 3;
  int bm = ((sq >> 3) * 8 + xc) * 128;   // m-tile
  int bn = (sq & 7) * 128;               // n-tile
  int wid = tid >> 6, lane = tid & 63;
  int wm = (wid >> 1) * 64, wn = (wid & 1) * 64;
  int mh = wid >> 1, nh = wid & 1;

  // staging addresses (round-0 verified swizzle)
  int pr = tid >> 3, pc = tid & 7;
  int lg = pc ^ (pr & 7);
  int mhalf = lg >> 2, kc = lg & 3;
  const ushort* gA1 = fh  + ((size_t)(bm + pr + 64 * mhalf) * NF2 + kc * 8);
  const ushort* gA2 = gA1 + (size_t)32 * NF2;
  const ushort* gB1 = W0t + ((size_t)(bn + pr + 64 * mhalf) * NF2 + kc * 8);
  const ushort* gB2 = gB1 + (size_t)32 * NF2;
  ushort* l0 = sh + tid * 8;             // this thread's 16B unit

#define STAGE(OFF) do {                        \
    glds16(gA1, l0 + (OFF));                   \
    glds16(gA2, l0 + (OFF) + 2048);            \
    glds16(gB1, l0 + (OFF) + 4096);            \
    glds16(gB2, l0 + (OFF) + 6144);            \
    gA1 += 32; gA2 += 32; gB1 += 32; gB2 += 32; } while (0)

  f32x4 acc[4][4];
#pragma unroll
  for (int i = 0; i < 4; ++i)
#pragma unroll
    for (int j = 0; j < 4; ++j) acc[i][j] = (f32x4){0.f, 0.f, 0.f, 0.f};

  // fragment read addresses (bytes, LDS, buffer 0)
  int mrow = lane & 15, qv = lane >> 4, h7 = mrow & 7;
  int pcA = ((mh << 2) | qv) ^ h7;
  int pcB = ((nh << 2) | qv) ^ h7;
  uint32_t lbase = (uint32_t)(size_t)(lds_ushort*)sh;
  uint32_t aA[4], aB[4];
#pragma unroll
  for (int i = 0; i < 4; ++i) {
    aA[i] = lbase + 2u * (uint32_t)((i * 16 + mrow) * 64 + pcA * 8);
    aB[i] = lbase + 2u * (uint32_t)(4096 + (i * 16 + mrow) * 64 + pcB * 8);
  }

  // prologue: tiles 0 (buf0) and 1 (buf1) staged; wait tile 0 only
  STAGE(0);
  STAGE(8192);
  asm volatile("s_waitcnt vmcnt(4)" ::: "memory");
  __builtin_amdgcn_s_barrier();

  const int NK = NF2 / 32;               // 80 K-steps
  int stoff = 16384;                     // ushort offset: buf for tile t+2
  uint32_t rboff = 0;                    // byte offset of read buffer (t%3)
  for (int t = 0; t < NK; ++t) {
    if (t + 2 < NK) {                    // stage tile t+2 (buffer freed at t-1)
      STAGE(stoff);
      stoff += 8192; if (stoff == 24576) stoff = 0;
    }
    f16x8 af[4], bf[4];
#pragma unroll
    for (int i = 0; i < 4; ++i) {
      af[i] = dsr(aA[i] + rboff);
      bf[i] = dsr(aB[i] + rboff);
    }
    asm volatile("s_waitcnt lgkmcnt(0)" ::: "memory");
    __builtin_amdgcn_sched_barrier(0);
#pragma unroll
    for (int i = 0; i < 4; ++i)
#pragma unroll
      for (int j = 0; j < 4; ++j)
        acc[i][j] = __builtin_amdgcn_mfma_f32_16x16x32_f16(af[i], bf[j], acc[i][j], 0, 0, 0);
    if (t + 2 < NK) {
      asm volatile("s_waitcnt vmcnt(4)" ::: "memory");   // tile t+1 landed
    } else if (t + 1 < NK) {
      asm volatile("s_waitcnt vmcnt(0)" ::: "memory");   // drain tail
    }
    if (t + 1 < NK) __builtin_amdgcn_s_barrier();
    rboff += 16384; if (rboff == 49152) rboff = 0;
  }
#undef STAGE

  int p = bn >> 8;
  int col = lane & 15, rbase = (lane >> 4) * 4;
#pragma unroll
  for (int i = 0; i < 4; ++i) {
#pragma unroll
    for (int r = 0; r < 4; ++r) {
      int m = bm + wm + i * 16 + rbase + r;
      bool live = (m < N_ATOMS);
      float pw = live ? combW[p * NS + species[m]] : 0.f;
#pragma unroll
      for (int j = 0; j < 4; ++j) {
        int n = bn + wn + j * 16 + col;
        float v = live ? silu(pw * acc[i][j][r]) : 0.f;
        h0f[(size_t)m * 1024 + n] = f2h(v);
      }
    }
  }
}

// ---------------- Kernel C: layer-1 MFMA, 64m x 256n(one p) per block ------
__global__ __launch_bounds__(256) void mlp1_mfma(
    const ushort* __restrict__ h0f, const ushort* __restrict__ W1t,
    const float* __restrict__ W2, const int* __restrict__ sid,
    float* __restrict__ out) {
  __shared__ ushort As[64 * 256];   // 32KB
  __shared__ float sout[NSTRUCT];
  int tid = threadIdx.x;
  int linear = blockIdx.x;                   // 0..639
  int xc = linear & 7, s = linear >> 3;      // s in [0,80)
  int p = s & 3, t = s >> 2;                 // t in [0,20)
  int bm = ((t >> 1) * 8 + xc) * 128 + (t & 1) * 64;   // 64-row tile
  int wid = tid >> 6, lane = tid & 63;
  int wn = wid * 64;                         // wave's n-quarter within p

  if (tid < NSTRUCT) sout[tid] = 0.f;

  int mrow = lane & 15;
  int qv = lane >> 4;
  int h7 = mrow & 7;

#pragma unroll
  for (int s8 = 0; s8 < 8; ++s8) {
    int d = s8 * 256 + tid;
    int r = d >> 5, pcs = d & 31;
    int lc = pcs ^ (r & 7);
    glds16(h0f + (size_t)(bm + r) * 1024 + p * 256 + lc * 8, As + d * 8);
  }

  const ushort* wb = W1t + (size_t)p * HID * HID;
  f16x8 breg[4][8];
#pragma unroll
  for (int j = 0; j < 4; ++j) {
    const ushort* row = wb + (size_t)(wn + j * 16 + mrow) * 256 + qv * 8;
#pragma unroll
    for (int ki = 0; ki < 8; ++ki)
      breg[j][ki] = *reinterpret_cast<const f16x8*>(row + ki * 32);
  }

  __syncthreads();   // drains glds16 + sout init visible

  f32x4 acc[4][4];
#pragma unroll
  for (int i = 0; i < 4; ++i)
#pragma unroll
    for (int j = 0; j < 4; ++j) acc[i][j] = (f32x4){0.f, 0.f, 0.f, 0.f};

#pragma unroll
  for (int ki = 0; ki < 8; ++ki) {
    f16x8 af[4];
#pragma unroll
    for (int i = 0; i < 4; ++i) {
      int row = i * 16 + mrow;
      int pc2 = (ki * 4 + qv) ^ h7;
      af[i] = *reinterpret_cast<const f16x8*>(&As[row * 256 + pc2 * 8]);
    }
#pragma unroll
    for (int i = 0; i < 4; ++i)
#pragma unroll
      for (int j = 0; j < 4; ++j)
        acc[i][j] = __builtin_amdgcn_mfma_f32_16x16x32_f16(af[i], breg[j][ki], acc[i][j], 0, 0, 0);
  }

  // fused layer-2 + segment-sum epilogue (LDS-staged)
  int col = lane & 15, quad = lane >> 4;
  float w2j[4];
#pragma unroll
  for (int j = 0; j < 4; ++j) w2j[j] = W2[p * 256 + wn + j * 16 + col];
#pragma unroll
  for (int i = 0; i < 4; ++i) {
#pragma unroll
    for (int r = 0; r < 4; ++r) {
      float v = silu(acc[i][0][r]) * w2j[0] + silu(acc[i][1][r]) * w2j[1]
              + silu(acc[i][2][r]) * w2j[2] + silu(acc[i][3][r]) * w2j[3];
      v += __shfl_xor(v, 1, 64);
      v += __shfl_xor(v, 2, 64);
      v += __shfl_xor(v, 4, 64);
      v += __shfl_xor(v, 8, 64);
      if (col == 0) {
        int m = bm + i * 16 + quad * 4 + r;
        if (m < N_ATOMS) atomicAdd(&sout[sid[m]], v);
      }
    }
  }
  __syncthreads();
  if (tid < NSTRUCT) {
    float v = sout[tid];
    if (v != 0.f) atomicAdd(&out[tid], v);
  }
}

extern "C" void kernel_launch(void* const* d_in, const int* in_sizes, int n_in,
                              void* d_out, int out_size, void* d_ws, size_t ws_size,
                              hipStream_t stream) {
  const float* c0      = (const float*)d_in[0];
  const float* c1      = (const float*)d_in[1];
  const float* c2      = (const float*)d_in[2];
  const float* c3      = (const float*)d_in[3];
  const int*   species = (const int*)d_in[4];
  const int*   sid     = (const int*)d_in[5];
  const float* combW   = (const float*)d_in[6];
  const float* W0      = (const float*)d_in[7];
  const float* W1      = (const float*)d_in[8];
  const float* W2      = (const float*)d_in[9];
  float*       out     = (float*)d_out;

  // ws: fh 52.4MB | W0t 5.2MB | W1t 0.5MB | h0f 21MB = ~79MB
  ushort* fh  = (ushort*)d_ws;
  ushort* W0t = fh  + (size_t)APAD * NF2;
  ushort* W1t = W0t + (size_t)NP * HID * NF2;
  ushort* h0f = W1t + (size_t)NP * HID * HID;

  prep_kernel<<<PB_TOTAL, 256, 0, stream>>>(c0, c1, c2, c3, W0, W1,
                                            fh, W0t, W1t, out);

  dim3 g2(8, APAD / 128);    // 8 n-tiles x 80 remapped slots
  gemm0_mfma<<<g2, 256, 0, stream>>>(fh, W0t, combW, species, h0f);

  mlp1_mfma<<<640, 256, 0, stream>>>(h0f, W1t, W2, sid, out);
}

// Round 4
// 196.205 us; speedup vs baseline: 1.0992x; 1.0992x over previous
//
#include <hip/hip_runtime.h>
#include <hip/hip_bf16.h>
#include <cstdint>
#include <cstddef>

#define N_ATOMS 10000
#define NSTRUCT 100
#define NP 4
#define NS 4
#define NF2 2560      // 4 l x 640 block-aligned symmetric-packed features
#define HID 256
#define APAD 10240    // 80 tiles of 128

// prep-kernel block ranges
#define PB_FEAT  2500                     // [0,2500): power spectrum, 4 atoms/block
#define PB_W0    (PB_FEAT + 2560)         // w0cvt: 8(n) x 80(k) x 4(p)
#define PB_W1    (PB_W0 + 256)            // w1cvt: 8 x 8 x 4
#define PB_ZERO  (PB_W1 + 300)            // fh tail rows 10000..10239
#define PB_TOTAL (PB_ZERO + 1)            // + out zero

typedef __attribute__((ext_vector_type(8))) _Float16 f16x8;
typedef __attribute__((ext_vector_type(8))) ushort u16x8;
typedef __attribute__((ext_vector_type(4))) float f32x4;

__device__ __forceinline__ float silu(float x) {
  return x / (1.f + __expf(-x));
}
__device__ __forceinline__ ushort f2h(float x) {
  _Float16 h = (_Float16)x;
  return *reinterpret_cast<ushort*>(&h);
}
// chunk c in [0,80) -> (row q, r-block b). Row q owns blocks q>>3 .. 3.
__device__ __forceinline__ void cdec(int c, int& q, int& b) {
  if (c < 32)      { q = c >> 2; b = c & 3; }
  else if (c < 56) { int x = c - 32; int j = (x * 171) >> 9; q = 8 + j; b = 1 + (x - j * 3); }
  else if (c < 72) { int x = c - 56; q = 16 + (x >> 1); b = 2 + (x & 1); }
  else             { q = 24 + (c - 72); b = 3; }
}

typedef __attribute__((address_space(3))) uint32_t lds_u32;
typedef const __attribute__((address_space(1))) uint32_t glb_u32;
__device__ __forceinline__ void glds16(const ushort* g, ushort* l) {
  __builtin_amdgcn_global_load_lds((glb_u32*)g, (lds_u32*)l, 16, 0, 0);
}

// ---------------- Kernel P: fused prep -------------------------------------
__global__ __launch_bounds__(256) void prep_kernel(
    const float* __restrict__ c0, const float* __restrict__ c1,
    const float* __restrict__ c2, const float* __restrict__ c3,
    const float* __restrict__ W0, const float* __restrict__ W1,
    ushort* __restrict__ fh, ushort* __restrict__ W0t,
    ushort* __restrict__ W1t, float* __restrict__ out) {
  __shared__ float shbuf[2048];   // feat: 4 waves x 512; cvt: 32x33
  int b = blockIdx.x;
  int tid = threadIdx.x;

  if (b < PB_FEAT) {
    // ---- power spectrum, one WAVE per atom, 5 chunks/lane ----
    int wv = tid >> 6, lane = tid & 63;
    int a = b * 4 + wv;
    float* cs = shbuf + wv * 512;
    for (int i = 0; i < 8; ++i) {
      int e = lane + i * 64;
      float v;
      if (e < 32)       v = c0[a * 32  + e];
      else if (e < 128) v = c1[a * 96  + (e - 32)];
      else if (e < 288) v = c2[a * 160 + (e - 128)];
      else              v = c3[a * 224 + (e - 288)];
      cs[e] = v;
    }
    __syncthreads();
    const float cg[4]  = {1.0f, 0.5773502691896258f, 0.4472135954999579f, 0.3779644730092272f};
    const int  off[4]  = {0, 32, 128, 288};
    const int  nm[4]   = {1, 3, 5, 7};
#pragma unroll
    for (int t = 0; t < 5; ++t) {
      int cc = lane + t * 64;           // [0,320), all lanes busy
      int l = cc / 80, c = cc - l * 80;
      int q, bb; cdec(c, q, bb);
      int rb = bb * 8;
      const float* base = cs + off[l];
      float s[8] = {0.f, 0.f, 0.f, 0.f, 0.f, 0.f, 0.f, 0.f};
      for (int m = 0; m < nm[l]; ++m) {
        float bq = base[m * 32 + q];
        float4 v0 = *reinterpret_cast<const float4*>(&base[m * 32 + rb]);
        float4 v1 = *reinterpret_cast<const float4*>(&base[m * 32 + rb + 4]);
        s[0] += bq * v0.x; s[1] += bq * v0.y; s[2] += bq * v0.z; s[3] += bq * v0.w;
        s[4] += bq * v1.x; s[5] += bq * v1.y; s[6] += bq * v1.z; s[7] += bq * v1.w;
      }
      u16x8 o;
#pragma unroll
      for (int u = 0; u < 8; ++u) o[u] = f2h(s[u] * cg[l]);
      *reinterpret_cast<u16x8*>(&fh[(size_t)a * NF2 + cc * 8]) = o;
    }
  } else if (b < PB_W0) {
    // ---- W0' fold -> W0t [p][h][fk] fp16 ----
    int idx = b - PB_FEAT;
    int nx = idx & 7;
    int rest = idx >> 3;
    int ky = rest % 80, p = rest / 80;
    int kt = ky * 32, nt = nx * 32;
    int lx = tid & 31, ly = tid >> 5;
    float (*t)[33] = (float(*)[33])shbuf;
    const float* src = W0 + (size_t)p * 4096 * HID;
#pragma unroll
    for (int i = 0; i < 4; ++i) {
      int kf = kt + ly + i * 8;
      int l = kf / 640, w = kf - l * 640;
      int c = w >> 3, s = w & 7;
      int q, bb; cdec(c, q, bb);
      int r = bb * 8 + s;
      float v = 0.f;
      if (r >= q) {
        v = src[(size_t)(l * 1024 + q * 32 + r) * HID + nt + lx];
        if (r > q) v += src[(size_t)(l * 1024 + r * 32 + q) * HID + nt + lx];
      }
      t[ly + i * 8][lx] = v;
    }
    __syncthreads();
    ushort* dst = W0t + (size_t)p * HID * NF2;
#pragma unroll
    for (int i = 0; i < 4; ++i)
      dst[(size_t)(nt + ly + i * 8) * NF2 + kt + lx] = f2h(t[lx][ly + i * 8]);
  } else if (b < PB_W1) {
    int idx = b - PB_W0;
    int nx = idx & 7, ky = (idx >> 3) & 7, p = idx >> 6;
    int kt = ky * 32, nt = nx * 32;
    int lx = tid & 31, ly = tid >> 5;
    float (*t)[33] = (float(*)[33])shbuf;
    const float* src = W1 + (size_t)p * HID * HID;
#pragma unroll
    for (int i = 0; i < 4; ++i)
      t[ly + i * 8][lx] = src[(size_t)(kt + ly + i * 8) * HID + nt + lx];
    __syncthreads();
    ushort* dst = W1t + (size_t)p * HID * HID;
#pragma unroll
    for (int i = 0; i < 4; ++i)
      dst[(size_t)(nt + ly + i * 8) * HID + kt + lx] = f2h(t[lx][ly + i * 8]);
  } else if (b < PB_ZERO) {
    int idx = b - PB_W1;
    size_t e = (size_t)idx * 2048 + tid * 8;
    u16x8 z = (u16x8){0, 0, 0, 0, 0, 0, 0, 0};
    *reinterpret_cast<u16x8*>(&fh[(size_t)N_ATOMS * NF2 + e]) = z;
  } else {
    if (tid < NSTRUCT) out[tid] = 0.f;
  }
}

// ---------------- Kernel B: fp16 MFMA GEMM0, 128x128, BK=32, K=2560 --------
// (round-0 structure restored verbatim: best measured 81 us; all explicit
// pipelining variants regressed — see journal rounds 1-3)
__global__ __launch_bounds__(256) void gemm0_mfma(
    const ushort* __restrict__ fh, const ushort* __restrict__ W0t,
    const float* __restrict__ combW, const int* __restrict__ species,
    ushort* __restrict__ h0f) {
  __shared__ ushort As[64 * 64];   // 8KB
  __shared__ ushort Bs[64 * 64];   // 8KB
  int tid = threadIdx.x;
  int linear = blockIdx.y * 8 + blockIdx.x;
  int xc = linear & 7, sq = linear >> 3;
  int bm = ((sq >> 3) * 8 + xc) * 128;   // m-tile
  int bn = (sq & 7) * 128;               // n-tile
  int wid = tid >> 6, lane = tid & 63;
  int wm = (wid >> 1) * 64, wn = (wid & 1) * 64;
  int mh = wid >> 1, nh = wid & 1;

  int pr = tid >> 3, pc = tid & 7;
  int lg = pc ^ (pr & 7);
  int mhalf = lg >> 2, kc = lg & 3;
  const ushort* gaA1 = fh  + ((size_t)(bm + pr + 64 * mhalf) * NF2 + kc * 8);
  const ushort* gaA2 = gaA1 + (size_t)32 * NF2;
  const ushort* gaB1 = W0t + ((size_t)(bn + pr + 64 * mhalf) * NF2 + kc * 8);
  const ushort* gaB2 = gaB1 + (size_t)32 * NF2;
  ushort* lA = As + tid * 8;
  ushort* lB = Bs + tid * 8;

  f32x4 acc[4][4];
#pragma unroll
  for (int i = 0; i < 4; ++i)
#pragma unroll
    for (int j = 0; j < 4; ++j) acc[i][j] = (f32x4){0.f, 0.f, 0.f, 0.f};

  int mrow = lane & 15;
  int h7 = mrow & 7;
  int qv = lane >> 4;
  int pcA = ((mh << 2) | qv) ^ h7;
  int pcB = ((nh << 2) | qv) ^ h7;

  for (int k0 = 0; k0 < NF2; k0 += 32) {
    glds16(gaA1 + k0, lA);
    glds16(gaA2 + k0, lA + 2048);
    glds16(gaB1 + k0, lB);
    glds16(gaB2 + k0, lB + 2048);
    __syncthreads();

    f16x8 af[4], bf[4];
#pragma unroll
    for (int i = 0; i < 4; ++i) {
      af[i] = *reinterpret_cast<const f16x8*>(&As[(i * 16 + mrow) * 64 + pcA * 8]);
      bf[i] = *reinterpret_cast<const f16x8*>(&Bs[(i * 16 + mrow) * 64 + pcB * 8]);
    }
#pragma unroll
    for (int i = 0; i < 4; ++i)
#pragma unroll
      for (int j = 0; j < 4; ++j)
        acc[i][j] = __builtin_amdgcn_mfma_f32_16x16x32_f16(af[i], bf[j], acc[i][j], 0, 0, 0);
    __syncthreads();
  }

  int p = bn >> 8;
  int col = lane & 15, rbase = (lane >> 4) * 4;
#pragma unroll
  for (int i = 0; i < 4; ++i) {
#pragma unroll
    for (int r = 0; r < 4; ++r) {
      int m = bm + wm + i * 16 + rbase + r;
      bool live = (m < N_ATOMS);
      float pw = live ? combW[p * NS + species[m]] : 0.f;
#pragma unroll
      for (int j = 0; j < 4; ++j) {
        int n = bn + wn + j * 16 + col;
        float v = live ? silu(pw * acc[i][j][r]) : 0.f;
        h0f[(size_t)m * 1024 + n] = f2h(v);
      }
    }
  }
}

// ---------------- Kernel C: layer-1 MFMA, 64m x 256n(one p) per block ------
// changes vs prior: (a) W1t fragments loaded per-ki with 1-deep prefetch
// (VGPR ~220 -> ~140); (b) epilogue uses run-length register accumulation
// over the SORTED sid, one LDS atomic per sid-run per lane instead of 16.
__global__ __launch_bounds__(256) void mlp1_mfma(
    const ushort* __restrict__ h0f, const ushort* __restrict__ W1t,
    const float* __restrict__ W2, const int* __restrict__ sid,
    float* __restrict__ out) {
  __shared__ ushort As[64 * 256];   // 32KB
  __shared__ float sout[NSTRUCT];
  int tid = threadIdx.x;
  int linear = blockIdx.x;                   // 0..639
  int xc = linear & 7, s = linear >> 3;      // s in [0,80)
  int p = s & 3, t = s >> 2;                 // t in [0,20)
  int bm = ((t >> 1) * 8 + xc) * 128 + (t & 1) * 64;   // 64-row tile
  int wid = tid >> 6, lane = tid & 63;
  int wn = wid * 64;                         // wave's n-quarter within p

  if (tid < NSTRUCT) sout[tid] = 0.f;

  int mrow = lane & 15;
  int qv = lane >> 4;
  int h7 = mrow & 7;

#pragma unroll
  for (int s8 = 0; s8 < 8; ++s8) {
    int d = s8 * 256 + tid;
    int r = d >> 5, pcs = d & 31;
    int lc = pcs ^ (r & 7);
    glds16(h0f + (size_t)(bm + r) * 1024 + p * 256 + lc * 8, As + d * 8);
  }

  const ushort* wb = W1t + (size_t)p * HID * HID;
  const ushort* wrow[4];
#pragma unroll
  for (int j = 0; j < 4; ++j)
    wrow[j] = wb + (size_t)(wn + j * 16 + mrow) * 256 + qv * 8;

  f16x8 bc[4], bn_[4];
#pragma unroll
  for (int j = 0; j < 4; ++j) bc[j] = *reinterpret_cast<const f16x8*>(wrow[j]);

  __syncthreads();   // drains glds16 + sout init visible

  f32x4 acc[4][4];
#pragma unroll
  for (int i = 0; i < 4; ++i)
#pragma unroll
    for (int j = 0; j < 4; ++j) acc[i][j] = (f32x4){0.f, 0.f, 0.f, 0.f};

#pragma unroll
  for (int ki = 0; ki < 8; ++ki) {
    if (ki < 7) {
#pragma unroll
      for (int j = 0; j < 4; ++j)
        bn_[j] = *reinterpret_cast<const f16x8*>(wrow[j] + (ki + 1) * 32);
    }
    f16x8 af[4];
#pragma unroll
    for (int i = 0; i < 4; ++i) {
      int row = i * 16 + mrow;
      int pc2 = (ki * 4 + qv) ^ h7;
      af[i] = *reinterpret_cast<const f16x8*>(&As[row * 256 + pc2 * 8]);
    }
#pragma unroll
    for (int i = 0; i < 4; ++i)
#pragma unroll
      for (int j = 0; j < 4; ++j)
        acc[i][j] = __builtin_amdgcn_mfma_f32_16x16x32_f16(af[i], bc[j], acc[i][j], 0, 0, 0);
    if (ki < 7) {
#pragma unroll
      for (int j = 0; j < 4; ++j) bc[j] = bn_[j];
    }
  }

  // fused layer-2 + segment-sum epilogue: run-length accumulate over sorted sid
  int col = lane & 15, quad = lane >> 4;
  float w2j[4];
#pragma unroll
  for (int j = 0; j < 4; ++j) w2j[j] = W2[p * 256 + wn + j * 16 + col];
  float runv = 0.f;
  int runs = -1;
#pragma unroll
  for (int i = 0; i < 4; ++i) {
#pragma unroll
    for (int r = 0; r < 4; ++r) {
      float v = silu(acc[i][0][r]) * w2j[0] + silu(acc[i][1][r]) * w2j[1]
              + silu(acc[i][2][r]) * w2j[2] + silu(acc[i][3][r]) * w2j[3];
      v += __shfl_xor(v, 1, 64);
      v += __shfl_xor(v, 2, 64);
      v += __shfl_xor(v, 4, 64);
      v += __shfl_xor(v, 8, 64);
      if (col == 0) {
        int m = bm + i * 16 + quad * 4 + r;       // strictly increasing in (i,r)
        int s_ = (m < N_ATOMS) ? sid[m] : -1;     // sorted, non-decreasing
        if (s_ != runs) {
          if (runs >= 0) atomicAdd(&sout[runs], runv);
          runs = s_;
          runv = 0.f;
        }
        if (s_ >= 0) runv += v;
      }
    }
  }
  if (col == 0 && runs >= 0) atomicAdd(&sout[runs], runv);

  __syncthreads();
  if (tid < NSTRUCT) {
    float v = sout[tid];
    if (v != 0.f) atomicAdd(&out[tid], v);
  }
}

extern "C" void kernel_launch(void* const* d_in, const int* in_sizes, int n_in,
                              void* d_out, int out_size, void* d_ws, size_t ws_size,
                              hipStream_t stream) {
  const float* c0      = (const float*)d_in[0];
  const float* c1      = (const float*)d_in[1];
  const float* c2      = (const float*)d_in[2];
  const float* c3      = (const float*)d_in[3];
  const int*   species = (const int*)d_in[4];
  const int*   sid     = (const int*)d_in[5];
  const float* combW   = (const float*)d_in[6];
  const float* W0      = (const float*)d_in[7];
  const float* W1      = (const float*)d_in[8];
  const float* W2      = (const float*)d_in[9];
  float*       out     = (float*)d_out;

  // ws: fh 52.4MB | W0t 5.2MB | W1t 0.5MB | h0f 21MB = ~79MB
  ushort* fh  = (ushort*)d_ws;
  ushort* W0t = fh  + (size_t)APAD * NF2;
  ushort* W1t = W0t + (size_t)NP * HID * NF2;
  ushort* h0f = W1t + (size_t)NP * HID * HID;

  prep_kernel<<<PB_TOTAL, 256, 0, stream>>>(c0, c1, c2, c3, W0, W1,
                                            fh, W0t, W1t, out);

  dim3 g2(8, APAD / 128);    // 8 n-tiles x 80 remapped slots
  gemm0_mfma<<<g2, 256, 0, stream>>>(fh, W0t, combW, species, h0f);

  mlp1_mfma<<<640, 256, 0, stream>>>(h0f, W1t, W2, sid, out);
}